// Round 2
// baseline (328.091 us; speedup 1.0000x reference)
//
#include <hip/hip_runtime.h>
#include <hip/hip_bf16.h>

typedef unsigned short u16;
using frag_ab = __attribute__((ext_vector_type(8))) short;
using f32x4   = __attribute__((ext_vector_type(4))) float;
using u16x8   = __attribute__((ext_vector_type(8))) unsigned short;

#define N_CTX   2048
#define NBATCH  2
#define CDIM    1024
#define NH      16
#define HD      64

__device__ __forceinline__ u16 f2b(float f) {
  __hip_bfloat16 h = __float2bfloat16(f);
  return __builtin_bit_cast(u16, h);
}

__device__ __forceinline__ f32x4 mfma16(frag_ab a, frag_ab b, f32x4 c) {
  return __builtin_amdgcn_mfma_f32_16x16x32_bf16(a, b, c, 0, 0, 0);
}

#define GLDS16(src, dst) \
  __builtin_amdgcn_global_load_lds((const __attribute__((address_space(1))) void*)(src), \
                                   (__attribute__((address_space(3))) void*)(dst), 16, 0, 0)

// ---------------- prep kernels ----------------
__global__ __launch_bounds__(256) void cvt_f32_bf16(const float* __restrict__ in,
                                                    u16* __restrict__ out, int n8) {
  int i = blockIdx.x * 256 + threadIdx.x;
  if (i >= n8) return;
  const f32x4* ip = (const f32x4*)in;
  f32x4 a = ip[2 * i], b2 = ip[2 * i + 1];
  u16x8 r;
  #pragma unroll
  for (int j = 0; j < 4; ++j) { r[j] = f2b(a[j]); r[4 + j] = f2b(b2[j]); }
  ((u16x8*)out)[i] = r;
}

// in: [K][N] f32  ->  out: [N][K] bf16
__global__ __launch_bounds__(256) void transpose_cvt(const float* __restrict__ in,
                                                     u16* __restrict__ out, int K, int N) {
  __shared__ float tile[32][33];
  int n0 = blockIdx.x * 32, k0 = blockIdx.y * 32;
  int c = threadIdx.x & 31, r0 = threadIdx.x >> 5;
  #pragma unroll
  for (int i = 0; i < 4; ++i) {
    int r = r0 + i * 8;
    tile[r][c] = in[(size_t)(k0 + r) * N + n0 + c];
  }
  __syncthreads();
  #pragma unroll
  for (int i = 0; i < 4; ++i) {
    int r = r0 + i * 8;
    out[(size_t)(n0 + r) * K + k0 + c] = f2b(tile[c][r]);
  }
}

// ---------------- 128x128 bf16 GEMM core (2-phase, global_load_lds staging) ----------------
// A: [M][K] bf16 row-major.  Bt: [N][K] bf16 (i.e. B transposed).  C = A @ B.
__device__ __forceinline__ void gemm_core_128(const u16* __restrict__ A, const u16* __restrict__ Bt,
                                              int K, int tm, int tn,
                                              u16* As, u16* Bs, f32x4 (&acc)[4][4]) {
  const int tid = threadIdx.x, w = tid >> 6, lane = tid & 63;
  const int g = lane >> 4, lr = lane & 15;
  const int wr = w >> 1, wc = w & 1;
  #pragma unroll
  for (int mi = 0; mi < 4; ++mi)
    #pragma unroll
    for (int ni = 0; ni < 4; ++ni)
      acc[mi][ni] = (f32x4){0.f, 0.f, 0.f, 0.f};
  const int nkt = K >> 6;
  for (int kt = 0; kt < nkt; ++kt) {
    const int k0 = kt << 6;
    __syncthreads();   // previous iteration's reads of As/Bs complete
    #pragma unroll
    for (int r2 = 0; r2 < 4; ++r2) {
      int ch = r2 * 256 + w * 64 + lane;            // 16B chunk index in the 128x64 tile
      GLDS16(A  + (size_t)(tm + (ch >> 3)) * K + k0 + (ch & 7) * 8,
             As + (size_t)(r2 * 256 + w * 64) * 8);
      GLDS16(Bt + (size_t)(tn + (ch >> 3)) * K + k0 + (ch & 7) * 8,
             Bs + (size_t)(r2 * 256 + w * 64) * 8);
    }
    __syncthreads();   // barrier drains vmcnt -> staged data visible
    #pragma unroll
    for (int ks = 0; ks < 2; ++ks) {
      frag_ab af[4], bf[4];
      #pragma unroll
      for (int mi = 0; mi < 4; ++mi)
        af[mi] = *(const frag_ab*)&As[(wr * 64 + mi * 16 + lr) * 64 + ks * 32 + g * 8];
      #pragma unroll
      for (int ni = 0; ni < 4; ++ni)
        bf[ni] = *(const frag_ab*)&Bs[(wc * 64 + ni * 16 + lr) * 64 + ks * 32 + g * 8];
      #pragma unroll
      for (int mi = 0; mi < 4; ++mi)
        #pragma unroll
        for (int ni = 0; ni < 4; ++ni)
          acc[mi][ni] = mfma16(af[mi], bf[ni], acc[mi][ni]);
    }
  }
}

// GEMM1: qkv = x @ W_attn + b_attn, scattered into Q/K [b,h,t,d] and V^T [b,h,d,t] bf16
__global__ __launch_bounds__(256) void gemm_qkv(const u16* __restrict__ A, const u16* __restrict__ Bt,
                                                const float* __restrict__ bias,
                                                u16* __restrict__ Qo, u16* __restrict__ Ko,
                                                u16* __restrict__ Vto) {
  __shared__ __align__(16) u16 As[128 * 64];
  __shared__ __align__(16) u16 Bs[128 * 64];
  const int tm = blockIdx.x * 128, tn = blockIdx.y * 128;
  f32x4 acc[4][4];
  gemm_core_128(A, Bt, CDIM, tm, tn, As, Bs, acc);
  const int tid = threadIdx.x, w = tid >> 6, lane = tid & 63;
  const int g = lane >> 4, lr = lane & 15;
  const int wr = w >> 1, wc = w & 1;
  #pragma unroll
  for (int ni = 0; ni < 4; ++ni) {
    int n = tn + wc * 64 + ni * 16 + lr;     // 0..3071
    float bv = bias[n];
    int which = n >> 10, c = n & 1023, h = c >> 6, d = c & 63;
    #pragma unroll
    for (int mi = 0; mi < 4; ++mi)
      #pragma unroll
      for (int r = 0; r < 4; ++r) {
        int m = tm + wr * 64 + mi * 16 + g * 4 + r;   // 0..4095
        int b = m >> 11, t = m & (N_CTX - 1);
        u16 val = f2b(acc[mi][ni][r] + bv);
        if (which == 2) {
          Vto[((size_t)(b * NH + h) * HD + d) * N_CTX + t] = val;       // V transposed
        } else {
          u16* dst = (which == 0) ? Qo : Ko;
          dst[((size_t)(b * NH + h) * N_CTX + t) * HD + d] = val;
        }
      }
  }
}

// GEMM2: out = y @ W_proj + b_proj  (fp32 out)
__global__ __launch_bounds__(256) void gemm_proj(const u16* __restrict__ A, const u16* __restrict__ Bt,
                                                 const float* __restrict__ bias,
                                                 float* __restrict__ out) {
  __shared__ __align__(16) u16 As[128 * 64];
  __shared__ __align__(16) u16 Bs[128 * 64];
  const int tm = blockIdx.x * 128, tn = blockIdx.y * 128;
  f32x4 acc[4][4];
  gemm_core_128(A, Bt, CDIM, tm, tn, As, Bs, acc);
  const int tid = threadIdx.x, w = tid >> 6, lane = tid & 63;
  const int g = lane >> 4, lr = lane & 15;
  const int wr = w >> 1, wc = w & 1;
  #pragma unroll
  for (int ni = 0; ni < 4; ++ni) {
    int n = tn + wc * 64 + ni * 16 + lr;
    float bv = bias[n];
    #pragma unroll
    for (int mi = 0; mi < 4; ++mi)
      #pragma unroll
      for (int r = 0; r < 4; ++r) {
        int m = tm + wr * 64 + mi * 16 + g * 4 + r;
        out[(size_t)m * CDIM + n] = acc[mi][ni][r] + bv;
      }
  }
}

// ---------------- flash attention (causal), no barriers in the k-loop ----------------
// Q,K: [bh][t][d].  Vt: [bh][d][t].  All fragments straight from global (L2-resident).
// Per-wave P roundtrip through private LDS region (same-wave lgkmcnt ordering only).
__global__ __launch_bounds__(256) void attn_fwd(const u16* __restrict__ Q, const u16* __restrict__ K,
                                                const u16* __restrict__ Vt, u16* __restrict__ Y) {
  __shared__ __align__(16) u16 Pl[4 * 16 * 72];    // per-wave P: [16 rows][64 kj], stride 72
  // XCD-bijective swizzle: 1024 blocks, 8 XCDs -> each XCD owns 4 consecutive bh
  // (K+V working set 4 x 512KB = 2MB per 4MB L2). qt reversed: heavy blocks first.
  const int orig = blockIdx.x;
  const int swz = (orig & 7) * 128 + (orig >> 3);
  const int qt = 31 - (swz & 31);
  const int bh = swz >> 5;
  const int tid = threadIdx.x, w = tid >> 6, lane = tid & 63;
  const int g = lane >> 4, lr = lane & 15;
  const size_t base = (size_t)bh * N_CTX * HD;

  // Q fragments (A-layout): row = lane&15 of this wave's 16-row block
  frag_ab qf[2];
  {
    const u16* qp = Q + base + (size_t)(qt * 64 + w * 16 + lr) * HD + g * 8;
    qf[0] = *(const frag_ab*)qp;
    qf[1] = *(const frag_ab*)(qp + 32);
  }
  float mr[4], lsum[4];
  f32x4 o[4];
  #pragma unroll
  for (int r = 0; r < 4; ++r) { mr[r] = -1e30f; lsum[r] = 0.f; }
  #pragma unroll
  for (int d = 0; d < 4; ++d) o[d] = (f32x4){0.f, 0.f, 0.f, 0.f};

  u16* Pw = Pl + w * 16 * 72;

  for (int kt = 0; kt <= qt; ++kt) {
    // S = Q K^T (scaled), K fragments straight from global
    f32x4 s[4];
    #pragma unroll
    for (int nf = 0; nf < 4; ++nf) {
      const u16* kp = K + base + (size_t)(kt * 64 + nf * 16 + lr) * HD + g * 8;
      frag_ab k0 = *(const frag_ab*)kp;
      frag_ab k1 = *(const frag_ab*)(kp + 32);
      f32x4 a = (f32x4){0.f, 0.f, 0.f, 0.f};
      a = mfma16(qf[0], k0, a);
      a = mfma16(qf[1], k1, a);
      s[nf] = a;
    }
    #pragma unroll
    for (int nf = 0; nf < 4; ++nf)
      #pragma unroll
      for (int r = 0; r < 4; ++r) {
        float v = s[nf][r] * 0.125f;
        if (kt == qt) {
          int col = nf * 16 + lr, row = w * 16 + g * 4 + r;
          if (col > row) v = -1e30f;
        }
        s[nf][r] = v;
      }

    // online softmax (rows live in 16-lane groups; butterfly over xor 1,2,4,8)
    float mt[4], al[4], ps[4];
    #pragma unroll
    for (int r = 0; r < 4; ++r) {
      mt[r] = fmaxf(fmaxf(s[0][r], s[1][r]), fmaxf(s[2][r], s[3][r]));
      #pragma unroll
      for (int x = 1; x < 16; x <<= 1) mt[r] = fmaxf(mt[r], __shfl_xor(mt[r], x, 64));
      float mn = fmaxf(mr[r], mt[r]);
      al[r] = __expf(mr[r] - mn);
      mr[r] = mn;
      ps[r] = 0.f;
    }
    #pragma unroll
    for (int nf = 0; nf < 4; ++nf)
      #pragma unroll
      for (int r = 0; r < 4; ++r) {
        float p = __expf(s[nf][r] - mr[r]);
        s[nf][r] = p;
        ps[r] += p;
      }
    #pragma unroll
    for (int r = 0; r < 4; ++r) {
      #pragma unroll
      for (int x = 1; x < 16; x <<= 1) ps[r] += __shfl_xor(ps[r], x, 64);
      lsum[r] = lsum[r] * al[r] + ps[r];
    }
    #pragma unroll
    for (int d = 0; d < 4; ++d)
      #pragma unroll
      for (int r = 0; r < 4; ++r) o[d][r] *= al[r];

    // P -> per-wave LDS (C-layout -> A-layout roundtrip), then O += P @ V
    #pragma unroll
    for (int nf = 0; nf < 4; ++nf)
      #pragma unroll
      for (int r = 0; r < 4; ++r)
        Pw[(g * 4 + r) * 72 + nf * 16 + lr] = f2b(s[nf][r]);
    #pragma unroll
    for (int ks = 0; ks < 2; ++ks) {
      frag_ab pa = *(const frag_ab*)&Pw[lr * 72 + ks * 32 + g * 8];
      #pragma unroll
      for (int d = 0; d < 4; ++d) {
        const u16* vp = Vt + base + (size_t)(d * 16 + lr) * N_CTX + kt * 64 + ks * 32 + g * 8;
        frag_ab vf = *(const frag_ab*)vp;
        o[d] = mfma16(pa, vf, o[d]);
      }
    }
  }

  // epilogue: O/l, back to [b][t][h*64+d] bf16
  const int b = bh >> 4, h = bh & 15;
  #pragma unroll
  for (int d = 0; d < 4; ++d)
    #pragma unroll
    for (int r = 0; r < 4; ++r) {
      int row = qt * 64 + w * 16 + g * 4 + r;
      float val = o[d][r] / lsum[r];
      Y[((size_t)(b * N_CTX + row)) * CDIM + h * HD + d * 16 + lr] = f2b(val);
    }
}

// ---------------- launch ----------------
extern "C" void kernel_launch(void* const* d_in, const int* in_sizes, int n_in,
                              void* d_out, int out_size, void* d_ws, size_t ws_size,
                              hipStream_t stream) {
  const float* x      = (const float*)d_in[0];
  const float* W_attn = (const float*)d_in[1];
  const float* b_attn = (const float*)d_in[2];
  const float* W_proj = (const float*)d_in[3];
  const float* b_proj = (const float*)d_in[4];
  float* out = (float*)d_out;
  char* ws = (char*)d_ws;

  u16* xb  = (u16*)(ws);                       // 8 MB  [4096][1024] bf16 (reused for y)
  u16* Wab = (u16*)(ws + ((size_t)8 << 20));   // 6 MB  [3072][1024] bf16 (W_attn^T)
  u16* Wpb = (u16*)(ws + ((size_t)14 << 20));  // 2 MB  [1024][1024] bf16 (W_proj^T)
  u16* Qb  = (u16*)(ws + ((size_t)16 << 20));  // 8 MB  [32][2048][64]
  u16* Kb  = (u16*)(ws + ((size_t)24 << 20));  // 8 MB  [32][2048][64]
  u16* Vtb = (u16*)(ws + ((size_t)32 << 20));  // 8 MB  [32][64][2048]  (V transposed)
  u16* yb  = xb;                                // x dead after gemm_qkv

  cvt_f32_bf16<<<2048, 256, 0, stream>>>(x, xb, (NBATCH * N_CTX * CDIM) / 8);
  transpose_cvt<<<dim3(3 * CDIM / 32, CDIM / 32), 256, 0, stream>>>(W_attn, Wab, CDIM, 3 * CDIM);
  transpose_cvt<<<dim3(CDIM / 32, CDIM / 32), 256, 0, stream>>>(W_proj, Wpb, CDIM, CDIM);
  gemm_qkv<<<dim3(32, 24), 256, 0, stream>>>(xb, Wab, b_attn, Qb, Kb, Vtb);
  attn_fwd<<<1024, 256, 0, stream>>>(Qb, Kb, Vtb, yb);
  gemm_proj<<<dim3(32, 8), 256, 0, stream>>>(yb, Wpb, b_proj, out);
}

// Round 3
// 160.213 us; speedup vs baseline: 2.0478x; 2.0478x over previous
//
#include <hip/hip_runtime.h>
#include <hip/hip_bf16.h>

typedef unsigned short u16;
using frag_ab = __attribute__((ext_vector_type(8))) short;
using f32x4   = __attribute__((ext_vector_type(4))) float;
using u16x4   = __attribute__((ext_vector_type(4))) unsigned short;
using u16x8   = __attribute__((ext_vector_type(8))) unsigned short;

#define N_CTX   2048
#define NBATCH  2
#define CDIM    1024
#define NH      16
#define HD      64

__device__ __forceinline__ u16 f2b(float f) {
  __hip_bfloat16 h = __float2bfloat16(f);
  return __builtin_bit_cast(u16, h);
}

__device__ __forceinline__ f32x4 mfma16(frag_ab a, frag_ab b, f32x4 c) {
  return __builtin_amdgcn_mfma_f32_16x16x32_bf16(a, b, c, 0, 0, 0);
}

#define GLDS16(src, dst) \
  __builtin_amdgcn_global_load_lds((const __attribute__((address_space(1))) void*)(src), \
                                   (__attribute__((address_space(3))) void*)(dst), 16, 0, 0)

// ---------------- prep kernels ----------------
__global__ __launch_bounds__(256) void cvt_f32_bf16(const float* __restrict__ in,
                                                    u16* __restrict__ out, int n8) {
  int i = blockIdx.x * 256 + threadIdx.x;
  if (i >= n8) return;
  const f32x4* ip = (const f32x4*)in;
  f32x4 a = ip[2 * i], b2 = ip[2 * i + 1];
  u16x8 r;
  #pragma unroll
  for (int j = 0; j < 4; ++j) { r[j] = f2b(a[j]); r[4 + j] = f2b(b2[j]); }
  ((u16x8*)out)[i] = r;
}

// in: [K][N] f32  ->  out: [N][K] bf16
__global__ __launch_bounds__(256) void transpose_cvt(const float* __restrict__ in,
                                                     u16* __restrict__ out, int K, int N) {
  __shared__ float tile[32][33];
  int n0 = blockIdx.x * 32, k0 = blockIdx.y * 32;
  int c = threadIdx.x & 31, r0 = threadIdx.x >> 5;
  #pragma unroll
  for (int i = 0; i < 4; ++i) {
    int r = r0 + i * 8;
    tile[r][c] = in[(size_t)(k0 + r) * N + n0 + c];
  }
  __syncthreads();
  #pragma unroll
  for (int i = 0; i < 4; ++i) {
    int r = r0 + i * 8;
    out[(size_t)(n0 + r) * K + k0 + c] = f2b(tile[c][r]);
  }
}

// ---------------- 128x128 bf16 GEMM core (2-phase, global_load_lds staging) ----------------
__device__ __forceinline__ void gemm_core_128(const u16* __restrict__ A, const u16* __restrict__ Bt,
                                              int K, int tm, int tn,
                                              u16* As, u16* Bs, f32x4 (&acc)[4][4]) {
  const int tid = threadIdx.x, w = tid >> 6, lane = tid & 63;
  const int g = lane >> 4, lr = lane & 15;
  const int wr = w >> 1, wc = w & 1;
  #pragma unroll
  for (int mi = 0; mi < 4; ++mi)
    #pragma unroll
    for (int ni = 0; ni < 4; ++ni)
      acc[mi][ni] = (f32x4){0.f, 0.f, 0.f, 0.f};
  const int nkt = K >> 6;
  for (int kt = 0; kt < nkt; ++kt) {
    const int k0 = kt << 6;
    __syncthreads();
    #pragma unroll
    for (int r2 = 0; r2 < 4; ++r2) {
      int ch = r2 * 256 + w * 64 + lane;
      GLDS16(A  + (size_t)(tm + (ch >> 3)) * K + k0 + (ch & 7) * 8,
             As + (size_t)(r2 * 256 + w * 64) * 8);
      GLDS16(Bt + (size_t)(tn + (ch >> 3)) * K + k0 + (ch & 7) * 8,
             Bs + (size_t)(r2 * 256 + w * 64) * 8);
    }
    __syncthreads();
    #pragma unroll
    for (int ks = 0; ks < 2; ++ks) {
      frag_ab af[4], bf[4];
      #pragma unroll
      for (int mi = 0; mi < 4; ++mi)
        af[mi] = *(const frag_ab*)&As[(wr * 64 + mi * 16 + lr) * 64 + ks * 32 + g * 8];
      #pragma unroll
      for (int ni = 0; ni < 4; ++ni)
        bf[ni] = *(const frag_ab*)&Bs[(wc * 64 + ni * 16 + lr) * 64 + ks * 32 + g * 8];
      #pragma unroll
      for (int mi = 0; mi < 4; ++mi)
        #pragma unroll
        for (int ni = 0; ni < 4; ++ni)
          acc[mi][ni] = mfma16(af[mi], bf[ni], acc[mi][ni]);
    }
  }
}

// GEMM1: qkv = x @ W_attn + b_attn -> Q/K [bh][t][d], V^T [bh][d][t]
__global__ __launch_bounds__(256) void gemm_qkv(const u16* __restrict__ A, const u16* __restrict__ Bt,
                                                const float* __restrict__ bias,
                                                u16* __restrict__ Qo, u16* __restrict__ Ko,
                                                u16* __restrict__ Vto) {
  __shared__ __align__(16) u16 As[128 * 64];
  __shared__ __align__(16) u16 Bs[128 * 64];
  const int tm = blockIdx.x * 128, tn = blockIdx.y * 128;
  f32x4 acc[4][4];
  gemm_core_128(A, Bt, CDIM, tm, tn, As, Bs, acc);
  const int tid = threadIdx.x, w = tid >> 6, lane = tid & 63;
  const int g = lane >> 4, lr = lane & 15;
  const int wr = w >> 1, wc = w & 1;
  #pragma unroll
  for (int ni = 0; ni < 4; ++ni) {
    int n = tn + wc * 64 + ni * 16 + lr;     // 0..3071
    float bv = bias[n];
    int which = n >> 10, c = n & 1023, h = c >> 6, d = c & 63;
    #pragma unroll
    for (int mi = 0; mi < 4; ++mi) {
      if (which == 2) {
        int t0 = tm + wr * 64 + mi * 16 + g * 4;       // aligned 4
        int b = t0 >> 11, t = t0 & (N_CTX - 1);
        u16x4 pk;
        #pragma unroll
        for (int r = 0; r < 4; ++r) pk[r] = f2b(acc[mi][ni][r] + bv);
        *(u16x4*)&Vto[((size_t)(b * NH + h) * HD + d) * N_CTX + t] = pk;
      } else {
        u16* dst = (which == 0) ? Qo : Ko;
        #pragma unroll
        for (int r = 0; r < 4; ++r) {
          int m = tm + wr * 64 + mi * 16 + g * 4 + r;
          int b = m >> 11, t = m & (N_CTX - 1);
          dst[((size_t)(b * NH + h) * N_CTX + t) * HD + d] = f2b(acc[mi][ni][r] + bv);
        }
      }
    }
  }
}

// GEMM2: out = y @ W_proj + b_proj  (fp32 out)
__global__ __launch_bounds__(256) void gemm_proj(const u16* __restrict__ A, const u16* __restrict__ Bt,
                                                 const float* __restrict__ bias,
                                                 float* __restrict__ out) {
  __shared__ __align__(16) u16 As[128 * 64];
  __shared__ __align__(16) u16 Bs[128 * 64];
  const int tm = blockIdx.x * 128, tn = blockIdx.y * 128;
  f32x4 acc[4][4];
  gemm_core_128(A, Bt, CDIM, tm, tn, As, Bs, acc);
  const int tid = threadIdx.x, w = tid >> 6, lane = tid & 63;
  const int g = lane >> 4, lr = lane & 15;
  const int wr = w >> 1, wc = w & 1;
  #pragma unroll
  for (int ni = 0; ni < 4; ++ni) {
    int n = tn + wc * 64 + ni * 16 + lr;
    float bv = bias[n];
    #pragma unroll
    for (int mi = 0; mi < 4; ++mi)
      #pragma unroll
      for (int r = 0; r < 4; ++r) {
        int m = tm + wr * 64 + mi * 16 + g * 4 + r;
        out[(size_t)m * CDIM + n] = acc[mi][ni][r] + bv;
      }
  }
}

// ---------------- flash attention (causal) ----------------
// Block = (bh, pair p): q-tiles {p, 31-p} -> every block does exactly 33 tile-units.
// K,V^T staged in double-buffered LDS via global_load_lds (2-phase prefetch),
// source-XOR-swizzled so ds_read_b128 fragments are bank-balanced (rule 21 / T2+T3).
__global__ __launch_bounds__(256) void attn_fwd(const u16* __restrict__ Q, const u16* __restrict__ K,
                                                const u16* __restrict__ Vt, u16* __restrict__ Y) {
  __shared__ __align__(16) u16 Ks[2][64 * 64];
  __shared__ __align__(16) u16 Vs[2][64 * 64];
  __shared__ __align__(16) u16 Pl[4 * 16 * 72];
  // 512 blocks = 8 XCDs x 64; each XCD owns 4 consecutive bh (K+V = 2MB per L2)
  const int orig = blockIdx.x;
  const int swz = (orig & 7) * 64 + (orig >> 3);
  const int bh = swz >> 4;
  const int p  = swz & 15;
  const int qta = p, qtb = 31 - p;
  const int tid = threadIdx.x, w = tid >> 6, lane = tid & 63;
  const int g = lane >> 4, lr = lane & 15;
  const size_t base = (size_t)bh * N_CTX * HD;
  const u16* Kbh = K + base;
  const u16* Vbh = Vt + base;

  // per-thread staging offsets (kt-invariant; source pre-swizzled, LDS linear)
  const int c8 = tid & 7;
  const int row0 = tid >> 3;            // rows 0..31
  const int row1 = row0 + 32;           // rows 32..63
  const size_t kOff0 = (size_t)row0 * HD + (size_t)((c8 ^ (row0 & 7)) * 8);
  const size_t kOff1 = (size_t)row1 * HD + (size_t)((c8 ^ (row1 & 7)) * 8);
  const size_t vOff0 = (size_t)row0 * N_CTX + (size_t)((c8 ^ (row0 & 7)) * 8);
  const size_t vOff1 = (size_t)row1 * N_CTX + (size_t)((c8 ^ (row1 & 7)) * 8);

  // Q fragments for both subtiles
  frag_ab qfA[2], qfB[2];
  {
    const u16* qa = Q + base + (size_t)(qta * 64 + w * 16 + lr) * HD + g * 8;
    qfA[0] = *(const frag_ab*)qa;  qfA[1] = *(const frag_ab*)(qa + 32);
    const u16* qb = Q + base + (size_t)(qtb * 64 + w * 16 + lr) * HD + g * 8;
    qfB[0] = *(const frag_ab*)qb;  qfB[1] = *(const frag_ab*)(qb + 32);
  }

  float mrA[4], lsA[4], mrB[4], lsB[4];
  f32x4 oA[4], oB[4];
  #pragma unroll
  for (int r = 0; r < 4; ++r) { mrA[r] = -1e30f; lsA[r] = 0.f; mrB[r] = -1e30f; lsB[r] = 0.f; }
  #pragma unroll
  for (int d = 0; d < 4; ++d) { oA[d] = (f32x4){0,0,0,0}; oB[d] = (f32x4){0,0,0,0}; }

  u16* Pw = Pl + w * 16 * 72;

  auto STAGE = [&](int b, int kt) {
    const u16* ks = Kbh + (size_t)kt * 64 * HD;
    const u16* vs = Vbh + (size_t)kt * 64;
    GLDS16(ks + kOff0, &Ks[b][(size_t)tid * 8]);
    GLDS16(ks + kOff1, &Ks[b][(size_t)(tid + 256) * 8]);
    GLDS16(vs + vOff0, &Vs[b][(size_t)tid * 8]);
    GLDS16(vs + vOff1, &Vs[b][(size_t)(tid + 256) * 8]);
  };

  // kf shared between subtiles
  frag_ab kf[4][2];

  auto process = [&](const frag_ab (&qf)[2], f32x4 (&o)[4], float (&mr)[4], float (&ls)[4],
                     bool diag, int buf) {
    f32x4 s[4];
    #pragma unroll
    for (int nf = 0; nf < 4; ++nf) {
      f32x4 a = (f32x4){0, 0, 0, 0};
      a = mfma16(qf[0], kf[nf][0], a);
      a = mfma16(qf[1], kf[nf][1], a);
      s[nf] = a;
    }
    #pragma unroll
    for (int nf = 0; nf < 4; ++nf)
      #pragma unroll
      for (int r = 0; r < 4; ++r) {
        float v = s[nf][r] * 0.125f;
        if (diag) {
          int col = nf * 16 + lr, row = w * 16 + g * 4 + r;
          if (col > row) v = -1e30f;
        }
        s[nf][r] = v;
      }
    float mt[4], al[4], ps[4];
    #pragma unroll
    for (int r = 0; r < 4; ++r) {
      mt[r] = fmaxf(fmaxf(s[0][r], s[1][r]), fmaxf(s[2][r], s[3][r]));
      #pragma unroll
      for (int x = 1; x < 16; x <<= 1) mt[r] = fmaxf(mt[r], __shfl_xor(mt[r], x, 64));
      float mn = fmaxf(mr[r], mt[r]);
      al[r] = __expf(mr[r] - mn);
      mr[r] = mn;
      ps[r] = 0.f;
    }
    #pragma unroll
    for (int nf = 0; nf < 4; ++nf)
      #pragma unroll
      for (int r = 0; r < 4; ++r) {
        float pv = __expf(s[nf][r] - mr[r]);
        s[nf][r] = pv;
        ps[r] += pv;
      }
    #pragma unroll
    for (int r = 0; r < 4; ++r) {
      #pragma unroll
      for (int x = 1; x < 16; x <<= 1) ps[r] += __shfl_xor(ps[r], x, 64);
      ls[r] = ls[r] * al[r] + ps[r];
    }
    #pragma unroll
    for (int d = 0; d < 4; ++d)
      #pragma unroll
      for (int r = 0; r < 4; ++r) o[d][r] *= al[r];
    // P roundtrip (per-wave region, same-wave in-order DS)
    #pragma unroll
    for (int nf = 0; nf < 4; ++nf)
      #pragma unroll
      for (int r = 0; r < 4; ++r)
        Pw[(g * 4 + r) * 72 + nf * 16 + lr] = f2b(s[nf][r]);
    #pragma unroll
    for (int ks = 0; ks < 2; ++ks) {
      frag_ab pa = *(const frag_ab*)&Pw[lr * 72 + ks * 32 + g * 8];
      #pragma unroll
      for (int d = 0; d < 4; ++d) {
        frag_ab vf = *(const frag_ab*)&Vs[buf][(size_t)(d * 16 + lr) * 64 +
                                              (size_t)((((ks << 2) | g) ^ (lr & 7)) * 8)];
        o[d] = mfma16(pa, vf, o[d]);
      }
    }
  };

  STAGE(0, 0);
  __syncthreads();
  int buf = 0;
  for (int kt = 0; kt <= qtb; ++kt) {
    if (kt < qtb) STAGE(buf ^ 1, kt + 1);
    // K fragments from LDS (swizzled read), shared by both subtiles
    #pragma unroll
    for (int nf = 0; nf < 4; ++nf)
      #pragma unroll
      for (int ks = 0; ks < 2; ++ks)
        kf[nf][ks] = *(const frag_ab*)&Ks[buf][(size_t)(nf * 16 + lr) * 64 +
                                               (size_t)((((ks << 2) | g) ^ (lr & 7)) * 8)];
    process(qfB, oB, mrB, lsB, kt == qtb, buf);
    if (kt <= qta) process(qfA, oA, mrA, lsA, kt == qta, buf);
    __syncthreads();   // also drains the prefetch DMA (vmcnt 0 before barrier)
    buf ^= 1;
  }

  // epilogue: O/l -> [b][t][h*64+d] bf16
  const int b = bh >> 4, h = bh & 15;
  #pragma unroll
  for (int d = 0; d < 4; ++d)
    #pragma unroll
    for (int r = 0; r < 4; ++r) {
      int rowA = qta * 64 + w * 16 + g * 4 + r;
      Y[((size_t)(b * N_CTX + rowA)) * CDIM + h * HD + d * 16 + lr] = f2b(oA[d][r] / lsA[r]);
      int rowB = qtb * 64 + w * 16 + g * 4 + r;
      Y[((size_t)(b * N_CTX + rowB)) * CDIM + h * HD + d * 16 + lr] = f2b(oB[d][r] / lsB[r]);
    }
}

// ---------------- launch ----------------
extern "C" void kernel_launch(void* const* d_in, const int* in_sizes, int n_in,
                              void* d_out, int out_size, void* d_ws, size_t ws_size,
                              hipStream_t stream) {
  const float* x      = (const float*)d_in[0];
  const float* W_attn = (const float*)d_in[1];
  const float* b_attn = (const float*)d_in[2];
  const float* W_proj = (const float*)d_in[3];
  const float* b_proj = (const float*)d_in[4];
  float* out = (float*)d_out;
  char* ws = (char*)d_ws;

  u16* xb  = (u16*)(ws);                       // 8 MB  [4096][1024] bf16 (reused for y)
  u16* Wab = (u16*)(ws + ((size_t)8 << 20));   // 6 MB  [3072][1024] bf16 (W_attn^T)
  u16* Wpb = (u16*)(ws + ((size_t)14 << 20));  // 2 MB  [1024][1024] bf16 (W_proj^T)
  u16* Qb  = (u16*)(ws + ((size_t)16 << 20));  // 8 MB  [32][2048][64]
  u16* Kb  = (u16*)(ws + ((size_t)24 << 20));  // 8 MB  [32][2048][64]
  u16* Vtb = (u16*)(ws + ((size_t)32 << 20));  // 8 MB  [32][64][2048]  (V transposed)
  u16* yb  = xb;                                // x dead after gemm_qkv

  cvt_f32_bf16<<<2048, 256, 0, stream>>>(x, xb, (NBATCH * N_CTX * CDIM) / 8);
  transpose_cvt<<<dim3(3 * CDIM / 32, CDIM / 32), 256, 0, stream>>>(W_attn, Wab, CDIM, 3 * CDIM);
  transpose_cvt<<<dim3(CDIM / 32, CDIM / 32), 256, 0, stream>>>(W_proj, Wpb, CDIM, CDIM);
  gemm_qkv<<<dim3(32, 24), 256, 0, stream>>>(xb, Wab, b_attn, Qb, Kb, Vtb);
  attn_fwd<<<512, 256, 0, stream>>>(Qb, Kb, Vtb, yb);
  gemm_proj<<<dim3(32, 8), 256, 0, stream>>>(yb, Wpb, b_proj, out);
}